// Round 15
// baseline (141.998 us; speedup 1.0000x reference)
//
#include <hip/hip_runtime.h>
#include <hip/hip_bf16.h>
#include <math.h>

#define D_L   256
#define L_L   64
#define K_C   8
#define BATCH 2048
#define NTOT  16384
#define ENC_COLS 1536
#define LOG2PI 1.8378770664093453f
#define L2E    1.4426950408889634f
#define LN2    0.6931471805599453f
#define C_HL2E 0.7213475204444817f   // 0.5 * log2(e)

typedef __attribute__((ext_vector_type(8)))  short short8;
typedef __attribute__((ext_vector_type(8)))  unsigned short ushort8;
typedef __attribute__((ext_vector_type(4)))  unsigned short ushort4_;
typedef __attribute__((ext_vector_type(4)))  float float4_;
typedef __attribute__((ext_vector_type(16))) float float16_;

#if defined(__has_builtin)
#  if __has_builtin(__builtin_amdgcn_exp2f)
#    define EXP2F(x) __builtin_amdgcn_exp2f(x)
#  endif
#  if __has_builtin(__builtin_amdgcn_logf)
#    define LOG2F(x) __builtin_amdgcn_logf(x)
#  endif
#endif
#ifndef EXP2F
#  define EXP2F(x) __expf((x) * LN2)
#endif
#ifndef LOG2F
#  define LOG2F(x) (__logf(x) * L2E)
#endif

// workspace layout (float offsets), total ~16.25 MB
#define OFF_PE    0                                 // 2048*1536 f32
#define OFF_H     (BATCH * ENC_COLS)                // 16384*64 bf16, MFMA-A-frag order
#define OFF_WET2  (OFF_H + NTOT * L_L / 2)          // 1536*256 bf16, B-frag order
#define OFF_WDT2  (OFF_WET2 + ENC_COLS * D_L / 2)   // 6144*64 bf16, B-frag order

// Per-block partial sums: overlay the WeT2 region (dead after k_enc).
// 1024 enc slots + 512 dec slots x 128B stride. No atomics anywhere
// (R8 finding: same-line device-scope atomics serialize at ~12ns each).
#define PART_STRIDE 32
#define N_PART_ENC  1024
#define N_PART_DEC  512
#define N_PART_TOT  (N_PART_ENC + N_PART_DEC)       // 1536

__device__ __forceinline__ unsigned short f2bf(float f) {
  unsigned u = __float_as_uint(f);
  return (unsigned short)((u + 0x7fffu + ((u >> 16) & 1u)) >> 16);
}

// ---------------------------------------------------------------------------
// prep: 192 uniform 64x64 tile blocks converting W's into MFMA-B-fragment
// order bf16. Fragment order per 64x64 (k x col) tile:
//   [dg 2][st 4][q 2][col 32][j 8], element = W[k = st*16+q*8+j][dg*32+col]
//   tiles 0..95:   Wd tile (comp,p,dt), cols p*2048+comp*256+dt*64, scale L2E on p>0
//   tiles 96..191: We tile (cblk,kc),  rows kc*64, cols cblk*64
// ---------------------------------------------------------------------------
__global__ __launch_bounds__(256) void k_prep(
    const float* __restrict__ We, const float* __restrict__ Wd,
    unsigned short* __restrict__ WeT2, unsigned short* __restrict__ WdT2)
{
  const int bid = blockIdx.x, t = threadIdx.x;

  const float* src; int C, rowbase, colbase; float scale;
  unsigned short* dst;
  if (bid < 96) {
    const int comp = bid / 12, p = (bid % 12) >> 2, dt = bid & 3;
    src = Wd; C = 6144; rowbase = 0;
    colbase = p * 2048 + comp * 256 + dt * 64;
    scale = p ? L2E : 1.0f;
    dst = WdT2 + (size_t)bid * 4096;            // tile idx == (comp*3+p)*4+dt == bid
  } else {
    const int idx = bid - 96;
    src = We; C = ENC_COLS; rowbase = (idx & 3) * 64;
    colbase = (idx >> 2) * 64;
    scale = 1.0f;
    dst = WeT2 + (size_t)idx * 4096;            // tile idx == cblk*4+kc
  }

  __shared__ float tile[64][65];
  {
    const int col = t & 63, w0 = t >> 6;
    #pragma unroll
    for (int i = 0; i < 16; ++i) {
      const int r = w0 + i * 4;
      tile[r][col] = src[(size_t)(rowbase + r) * C + colbase + col] * scale;
    }
  }
  __syncthreads();
  const int st = t >> 6, q = (t >> 5) & 1, c = t & 31;
  #pragma unroll
  for (int dg = 0; dg < 2; ++dg) {
    ushort8 o;
    #pragma unroll
    for (int j = 0; j < 8; ++j) o[j] = f2bf(tile[st * 16 + q * 8 + j][dg * 32 + c]);
    *(ushort8*)(dst + ((((size_t)dg * 4 + st) * 2 + q) * 32 + c) * 8) = o;
  }
}

// ---------------------------------------------------------------------------
// Encoder GEMM: pe = x @ We + be. 64x64 tile, full K=256 staged in LDS once
// (single barrier), B-fragments streamed from L2. grid (24, 32) x 256.
// ---------------------------------------------------------------------------
__global__ __launch_bounds__(256) void k_enc(
    const float* __restrict__ x, const unsigned short* __restrict__ WeT2,
    const float* __restrict__ be, float* __restrict__ pe)
{
  __shared__ __align__(16) unsigned short as_[64 * 264];
  const int t = threadIdx.x;
  const int w = t >> 6, l = t & 63;
  const int col = l & 31, q = l >> 5;
  const int rg = w >> 1, dg = w & 1;
  const int m0 = blockIdx.y * 64, cblk = blockIdx.x, c0 = cblk * 64;

  // stage x tile (64 rows x 256 k) f32 -> bf16, coalesced
  {
    const int kc4 = (t & 63) * 4;
    #pragma unroll
    for (int i = 0; i < 16; ++i) {
      const int r = (t >> 6) + i * 4;
      float4_ v = *(const float4_*)(x + (size_t)(m0 + r) * D_L + kc4);
      ushort4_ o;
      o[0] = f2bf(v[0]); o[1] = f2bf(v[1]); o[2] = f2bf(v[2]); o[3] = f2bf(v[3]);
      *(ushort4_*)&as_[r * 264 + kc4] = o;
    }
  }

  const float bias = be[c0 + dg * 32 + col];
  float16_ acc;
  #pragma unroll
  for (int e = 0; e < 16; ++e) acc[e] = bias;

  __syncthreads();  // the only barrier

  const unsigned short* arow = &as_[(rg * 32 + col) * 264 + q * 8];
  const unsigned short* bbase = WeT2 + (size_t)cblk * 16384 + dg * 2048 + l * 8;
  #pragma unroll
  for (int kc = 0; kc < 4; ++kc) {
    #pragma unroll
    for (int st = 0; st < 4; ++st) {
      short8 a = *(const short8*)(arow + kc * 64 + st * 16);
      short8 b = *(const short8*)(bbase + (size_t)kc * 4096 + st * 512);
      acc = __builtin_amdgcn_mfma_f32_32x32x16_bf16(a, b, acc, 0, 0, 0);
    }
  }
  #pragma unroll
  for (int e = 0; e < 16; ++e) {
    const int row = (e & 3) + 8 * (e >> 2) + 4 * q;
    pe[(size_t)(m0 + rg * 32 + row) * ENC_COLS + c0 + dg * 32 + col] = acc[e];
  }
}

// ---------------------------------------------------------------------------
// Encoder post: sample + h (bf16, decoder-A-fragment global order) + Σ(Lq-Le).
// TWO waves per batch row (4 replicas each), 4096 waves = 4/SIMD.
// Block partial written to a private padded slot (NO atomics).
// grid 1024 x 256. h layout: [nblk 256][rg 2][st 4][q 2][col 32][j 8]
// ---------------------------------------------------------------------------
__global__ __launch_bounds__(256) void k_enc_post(
    const float* __restrict__ pe, const float* __restrict__ ue,
    const float* __restrict__ rr, unsigned short* __restrict__ h,
    float* __restrict__ part)
{
  const int lane = threadIdx.x & 63;
  const int w = threadIdx.x >> 6;
  const int gid = blockIdx.x * 4 + w;   // 0..4095
  const int b = gid >> 1;               // batch row
  const int j0 = (gid & 1) * 4;         // this wave's replica group
  const float* row = pe + (size_t)b * ENC_COLS + lane;

  float m[8], p[8], a[8];
  #pragma unroll
  for (int k = 0; k < K_C; ++k) {
    m[k] = row[k * 64]; p[k] = row[512 + k * 64]; a[k] = row[1024 + k * 64];
  }
  float amax = a[0];
  #pragma unroll
  for (int k = 1; k < K_C; ++k) amax = fmaxf(amax, a[k]);
  float sa = 0.f;
  #pragma unroll
  for (int k = 0; k < K_C; ++k) sa += __expf(a[k] - amax);
  const float lse_a = amax + __logf(sa);

  float cum[8];
  {
    float cs = 0.f;
    #pragma unroll
    for (int k = 0; k < K_C; ++k) { cs += __expf(a[k] - lse_a); cum[k] = cs; }
  }
  float ep[8];
  #pragma unroll
  for (int k = 0; k < K_C; ++k) ep[k] = __expf(p[k]);

  // this lane's fragment slot within a row's 64 k-values
  const int st = lane >> 4, qq = (lane >> 3) & 1, jj = lane & 7;

  float tot = 0.f;
  for (int jr = 0; jr < 4; ++jr) {
    const int j = j0 + jr;
    const int n = b + BATCH * j;
    const float rv = rr[(size_t)n * L_L + lane];
    const float uv = ue[(size_t)n * L_L + lane];
    int idx = 0;
    #pragma unroll
    for (int k = 0; k < K_C; ++k) idx += (rv > cum[k]) ? 1 : 0;
    idx = min(idx, K_C - 1);
    float msel = m[0], psel = p[0];
    #pragma unroll
    for (int k = 1; k < K_C; ++k) {
      const bool sel = (idx == k);
      msel = sel ? m[k] : msel;
      psel = sel ? p[k] : psel;
    }
    const float hv = fmaf(__expf(-0.5f * psel), uv, msel);

    const int nblk = n >> 6, rgn = (n >> 5) & 1, coln = n & 31;
    h[((((size_t)(nblk * 2 + rgn) * 4 + st) * 2 + qq) * 32 + coln) * 8 + jj] = f2bf(hv);

    float stt = 0.f;
    #pragma unroll
    for (int k = 0; k < K_C; ++k) {
      const float dd = hv - m[k];
      const float tt = a[k] + 0.5f * p[k] - 0.5f * ep[k] * dd * dd;
      stt += __expf(tt);
    }
    tot += -0.5f * hv * hv - (__logf(stt + 1e-30f) - lse_a);
  }
  #pragma unroll
  for (int off = 1; off < 64; off <<= 1) tot += __shfl_xor(tot, off, 64);
  __shared__ float red2[4];
  if (lane == 0) red2[w] = tot;
  __syncthreads();
  if (threadIdx.x == 0)
    part[(size_t)blockIdx.x * PART_STRIDE] = red2[0] + red2[1] + red2[2] + red2[3];
}

// ---------------------------------------------------------------------------
// Decoder: barrier-free fused MFMA GEMM + mixture epilogue.
// R13: BM=128 - each wave processes TWO 64-row tiles with the SAME
// B-fragments (grid (4,128) x 256, 512 blocks, all co-resident at 2/CU).
// Halves the dominant cost: B-fragment L2 traffic 393->196 MB (~11->5.7 us
// floor at 34.5 TB/s). am/ap/aa registers shared between the two row-sets
// (epilogue0 drains before MFMA set 1) to stay under the (256,2) reg cap.
// Biases (colD-only) load once per comp for both sets. Prefetch of comp+1
// B-frags kept (R10: neutral standalone, free here). No atomics.
// Occupancy ledger: 1-wave==4-wave (R1/R3), forced 3 waves regressed (R12)
// -> wave count is not the lever; traffic is.
// ---------------------------------------------------------------------------
__global__ __launch_bounds__(256, 2) void k_dec(
    const unsigned short* __restrict__ hF, const float* __restrict__ x,
    const unsigned short* __restrict__ WdT2, const float* __restrict__ bd,
    float* __restrict__ part)
{
  const int t = threadIdx.x;
  const int w = t >> 6, l = t & 63;
  const int col = l & 31, q = l >> 5;
  const int rg = w >> 1, dg = w & 1;
  const int dt = blockIdx.x, d0 = dt * 64;
  const int nb2 = blockIdx.y;             // 0..127, row-tiles {2*nb2, 2*nb2+1}
  const int colD = d0 + dg * 32 + col;

  // A fragments for both row-tiles: 8 coalesced 16B loads
  const unsigned short* hb0 = hF + ((size_t)((2 * nb2) * 2 + rg) * 4) * 512 + l * 8;
  const unsigned short* hb1 = hF + ((size_t)((2 * nb2 + 1) * 2 + rg) * 4) * 512 + l * 8;
  short8 af0[4], af1[4];
  #pragma unroll
  for (int st = 0; st < 4; ++st) {
    af0[st] = *(const short8*)(hb0 + st * 512);
    af1[st] = *(const short8*)(hb1 + st * 512);
  }

  // x values for this lane's 2x16 C-elements (reused across all comps)
  float xv0[16], xv1[16];
  #pragma unroll
  for (int e = 0; e < 16; ++e) {
    const int rw = (e & 3) + 8 * (e >> 2) + 4 * q;
    const int n0 = nb2 * 128 + rg * 32 + rw;
    xv0[e] = x[(size_t)(n0 & (BATCH - 1)) * D_L + colD];
    xv1[e] = x[(size_t)((n0 + 64) & (BATCH - 1)) * D_L + colD];
  }

  float s_a0[16], s_t0[16], s_a1[16], s_t1[16];
  #pragma unroll
  for (int e = 0; e < 16; ++e) {
    s_a0[e] = 0.f; s_t0[e] = 0.f; s_a1[e] = 0.f; s_t1[e] = 0.f;
  }

  const unsigned short* wbase = WdT2 + dg * 2048 + l * 8;
  const float* bdc = bd + colD;

  // prologue: comp 0's fragments + biases
  short8 bf[3][4];
  #pragma unroll
  for (int p = 0; p < 3; ++p) {
    const unsigned short* pb = wbase + ((size_t)p * 4 + dt) * 4096;
    #pragma unroll
    for (int st = 0; st < 4; ++st) bf[p][st] = *(const short8*)(pb + st * 512);
  }
  float bm  = bdc[0];
  float bpL = bdc[2048] * L2E;
  float baL = bdc[4096] * L2E;

  #pragma unroll 1
  for (int comp = 0; comp < K_C; ++comp) {
    const float cbm = bm, cbpL = bpL, cbaL = baL;

    // ---- row-set 0 ----
    float16_ am = {}, ap = {}, aa = {};
    #pragma unroll
    for (int st = 0; st < 4; ++st) {
      am = __builtin_amdgcn_mfma_f32_32x32x16_bf16(af0[st], bf[0][st], am, 0, 0, 0);
      ap = __builtin_amdgcn_mfma_f32_32x32x16_bf16(af0[st], bf[1][st], ap, 0, 0, 0);
      aa = __builtin_amdgcn_mfma_f32_32x32x16_bf16(af0[st], bf[2][st], aa, 0, 0, 0);
    }
    #pragma unroll
    for (int e = 0; e < 16; ++e) {
      const float dd  = xv0[e] - (am[e] + cbm);
      const float lpL = ap[e] + cbpL;
      const float laL = aa[e] + cbaL;
      const float ex2 = EXP2F(lpL);
      const float t1  = fmaf(0.5f, lpL, laL);
      const float ttL = fmaf(-C_HL2E * ex2, dd * dd, t1);
      s_a0[e] += EXP2F(laL);
      s_t0[e] += EXP2F(ttL);
    }

    // ---- row-set 1 (same B-fragments, acc registers reused) ----
    am = {}; ap = {}; aa = {};
    #pragma unroll
    for (int st = 0; st < 4; ++st) {
      am = __builtin_amdgcn_mfma_f32_32x32x16_bf16(af1[st], bf[0][st], am, 0, 0, 0);
      ap = __builtin_amdgcn_mfma_f32_32x32x16_bf16(af1[st], bf[1][st], ap, 0, 0, 0);
      aa = __builtin_amdgcn_mfma_f32_32x32x16_bf16(af1[st], bf[2][st], aa, 0, 0, 0);
    }

    // issue-early: next comp's loads fly while epilogue 1 runs
    if (comp + 1 < K_C) {
      #pragma unroll
      for (int p = 0; p < 3; ++p) {
        const unsigned short* pb =
            wbase + ((size_t)((comp + 1) * 3 + p) * 4 + dt) * 4096;
        #pragma unroll
        for (int st = 0; st < 4; ++st) bf[p][st] = *(const short8*)(pb + st * 512);
      }
      bm  = bdc[(comp + 1) * 256];
      bpL = bdc[2048 + (comp + 1) * 256] * L2E;
      baL = bdc[4096 + (comp + 1) * 256] * L2E;
    }

    #pragma unroll
    for (int e = 0; e < 16; ++e) {
      const float dd  = xv1[e] - (am[e] + cbm);
      const float lpL = ap[e] + cbpL;
      const float laL = aa[e] + cbaL;
      const float ex2 = EXP2F(lpL);
      const float t1  = fmaf(0.5f, lpL, laL);
      const float ttL = fmaf(-C_HL2E * ex2, dd * dd, t1);
      s_a1[e] += EXP2F(laL);
      s_t1[e] += EXP2F(ttL);
    }
  }

  float v = 0.f;
  #pragma unroll
  for (int e = 0; e < 16; ++e) {
    v += LOG2F(s_t0[e] + 1e-30f) - LOG2F(s_a0[e]);
    v += LOG2F(s_t1[e] + 1e-30f) - LOG2F(s_a1[e]);
  }
  v *= LN2;
  #pragma unroll
  for (int off = 1; off < 64; off <<= 1) v += __shfl_xor(v, off, 64);
  __shared__ float red[4];
  if (l == 0) red[w] = v;
  __syncthreads();
  if (t == 0) {
    const int bid = (blockIdx.y << 2) | blockIdx.x;   // 0..511
    part[(size_t)(N_PART_ENC + bid) * PART_STRIDE] = red[0] + red[1] + red[2] + red[3];
  }
}

// ---------------------------------------------------------------------------
// final: reduce 1536 padded partials (coalesced 128B-stride reads) -> out.
// ---------------------------------------------------------------------------
__global__ __launch_bounds__(256) void k_final(
    const float* __restrict__ part, float* __restrict__ out)
{
  const int t = threadIdx.x;
  float s = 0.f;
  #pragma unroll
  for (int i = 0; i < N_PART_TOT / 256; ++i)
    s += part[(size_t)(t + i * 256) * PART_STRIDE];
  #pragma unroll
  for (int off = 1; off < 64; off <<= 1) s += __shfl_xor(s, off, 64);
  __shared__ float red[4];
  if ((t & 63) == 0) red[t >> 6] = s;
  __syncthreads();
  if (t == 0)
    out[0] = -((red[0] + red[1] + red[2] + red[3]) / (float)NTOT) + 128.0f * LOG2PI;
}

// ---------------------------------------------------------------------------
extern "C" void kernel_launch(void* const* d_in, const int* in_sizes, int n_in,
                              void* d_out, int out_size, void* d_ws, size_t ws_size,
                              hipStream_t stream)
{
  const float* x  = (const float*)d_in[0];
  const float* We = (const float*)d_in[1];
  const float* be = (const float*)d_in[2];
  const float* Wd = (const float*)d_in[3];
  const float* bd = (const float*)d_in[4];
  const float* ue = (const float*)d_in[5];
  const float* rr = (const float*)d_in[6];
  float* out = (float*)d_out;

  float* ws = (float*)d_ws;
  float* pe            = ws + OFF_PE;
  unsigned short* h    = (unsigned short*)(ws + OFF_H);
  unsigned short* WeT2 = (unsigned short*)(ws + OFF_WET2);
  unsigned short* WdT2 = (unsigned short*)(ws + OFF_WDT2);
  // partials overlay WeT2 (dead after k_enc); every slot rewritten per replay
  float* part          = ws + OFF_WET2;

  k_prep<<<dim3(192), 256, 0, stream>>>(We, Wd, WeT2, WdT2);
  k_enc<<<dim3(ENC_COLS / 64, BATCH / 64), 256, 0, stream>>>(x, WeT2, be, pe);
  k_enc_post<<<dim3(BATCH / 2), 256, 0, stream>>>(pe, ue, rr, h, part);
  k_dec<<<dim3(4, NTOT / 128), 256, 0, stream>>>(h, x, WdT2, bd, part);
  k_final<<<dim3(1), 256, 0, stream>>>(part, out);
}

// Round 17
// 118.969 us; speedup vs baseline: 1.1936x; 1.1936x over previous
//
#include <hip/hip_runtime.h>
#include <hip/hip_bf16.h>
#include <math.h>

#define D_L   256
#define L_L   64
#define K_C   8
#define BATCH 2048
#define NTOT  16384
#define ENC_COLS 1536
#define LOG2PI 1.8378770664093453f
#define L2E    1.4426950408889634f
#define LN2    0.6931471805599453f
#define C_HL2E 0.7213475204444817f   // 0.5 * log2(e)

typedef __attribute__((ext_vector_type(8)))  short short8;
typedef __attribute__((ext_vector_type(8)))  unsigned short ushort8;
typedef __attribute__((ext_vector_type(4)))  unsigned short ushort4_;
typedef __attribute__((ext_vector_type(4)))  float float4_;
typedef __attribute__((ext_vector_type(16))) float float16_;

#if defined(__has_builtin)
#  if __has_builtin(__builtin_amdgcn_exp2f)
#    define EXP2F(x) __builtin_amdgcn_exp2f(x)
#  endif
#  if __has_builtin(__builtin_amdgcn_logf)
#    define LOG2F(x) __builtin_amdgcn_logf(x)
#  endif
#endif
#ifndef EXP2F
#  define EXP2F(x) __expf((x) * LN2)
#endif
#ifndef LOG2F
#  define LOG2F(x) (__logf(x) * L2E)
#endif

// workspace layout (float offsets), total ~16.25 MB
#define OFF_PE    0                                 // 2048*1536 f32
#define OFF_H     (BATCH * ENC_COLS)                // 16384*64 bf16, MFMA-A-frag order
#define OFF_WET2  (OFF_H + NTOT * L_L / 2)          // 1536*256 bf16, B-frag order
#define OFF_WDT2  (OFF_WET2 + ENC_COLS * D_L / 2)   // 6144*64 bf16, B-frag order

// Per-block partial sums: overlay the WeT2 region (dead after k_enc).
// 1024 enc + 1024 dec slots x 128B stride. No atomics anywhere
// (R8 finding: same-line device-scope atomics serialize at ~12ns each).
#define PART_STRIDE 32
#define N_PART_ENC  1024
#define N_PART_DEC  1024
#define N_PART_TOT  (N_PART_ENC + N_PART_DEC)       // 2048

__device__ __forceinline__ unsigned short f2bf(float f) {
  unsigned u = __float_as_uint(f);
  return (unsigned short)((u + 0x7fffu + ((u >> 16) & 1u)) >> 16);
}

// ---------------------------------------------------------------------------
// prep: 192 uniform 64x64 tile blocks converting W's into MFMA-B-fragment
// order bf16. Fragment order per 64x64 (k x col) tile:
//   [dg 2][st 4][q 2][col 32][j 8], element = W[k = st*16+q*8+j][dg*32+col]
//   tiles 0..95:   Wd tile (comp,p,dt), cols p*2048+comp*256+dt*64, scale L2E on p>0
//   tiles 96..191: We tile (cblk,kc),  rows kc*64, cols cblk*64
// ---------------------------------------------------------------------------
__global__ __launch_bounds__(256) void k_prep(
    const float* __restrict__ We, const float* __restrict__ Wd,
    unsigned short* __restrict__ WeT2, unsigned short* __restrict__ WdT2)
{
  const int bid = blockIdx.x, t = threadIdx.x;

  const float* src; int C, rowbase, colbase; float scale;
  unsigned short* dst;
  if (bid < 96) {
    const int comp = bid / 12, p = (bid % 12) >> 2, dt = bid & 3;
    src = Wd; C = 6144; rowbase = 0;
    colbase = p * 2048 + comp * 256 + dt * 64;
    scale = p ? L2E : 1.0f;
    dst = WdT2 + (size_t)bid * 4096;            // tile idx == (comp*3+p)*4+dt == bid
  } else {
    const int idx = bid - 96;
    src = We; C = ENC_COLS; rowbase = (idx & 3) * 64;
    colbase = (idx >> 2) * 64;
    scale = 1.0f;
    dst = WeT2 + (size_t)idx * 4096;            // tile idx == cblk*4+kc
  }

  __shared__ float tile[64][65];
  {
    const int col = t & 63, w0 = t >> 6;
    #pragma unroll
    for (int i = 0; i < 16; ++i) {
      const int r = w0 + i * 4;
      tile[r][col] = src[(size_t)(rowbase + r) * C + colbase + col] * scale;
    }
  }
  __syncthreads();
  const int st = t >> 6, q = (t >> 5) & 1, c = t & 31;
  #pragma unroll
  for (int dg = 0; dg < 2; ++dg) {
    ushort8 o;
    #pragma unroll
    for (int j = 0; j < 8; ++j) o[j] = f2bf(tile[st * 16 + q * 8 + j][dg * 32 + c]);
    *(ushort8*)(dst + ((((size_t)dg * 4 + st) * 2 + q) * 32 + c) * 8) = o;
  }
}

// ---------------------------------------------------------------------------
// Encoder GEMM: pe = x @ We + be. 64x64 tile, full K=256 staged in LDS once
// (single barrier), B-fragments streamed from L2. grid (24, 32) x 256.
// ---------------------------------------------------------------------------
__global__ __launch_bounds__(256) void k_enc(
    const float* __restrict__ x, const unsigned short* __restrict__ WeT2,
    const float* __restrict__ be, float* __restrict__ pe)
{
  __shared__ __align__(16) unsigned short as_[64 * 264];
  const int t = threadIdx.x;
  const int w = t >> 6, l = t & 63;
  const int col = l & 31, q = l >> 5;
  const int rg = w >> 1, dg = w & 1;
  const int m0 = blockIdx.y * 64, cblk = blockIdx.x, c0 = cblk * 64;

  // stage x tile (64 rows x 256 k) f32 -> bf16, coalesced
  {
    const int kc4 = (t & 63) * 4;
    #pragma unroll
    for (int i = 0; i < 16; ++i) {
      const int r = (t >> 6) + i * 4;
      float4_ v = *(const float4_*)(x + (size_t)(m0 + r) * D_L + kc4);
      ushort4_ o;
      o[0] = f2bf(v[0]); o[1] = f2bf(v[1]); o[2] = f2bf(v[2]); o[3] = f2bf(v[3]);
      *(ushort4_*)&as_[r * 264 + kc4] = o;
    }
  }

  const float bias = be[c0 + dg * 32 + col];
  float16_ acc;
  #pragma unroll
  for (int e = 0; e < 16; ++e) acc[e] = bias;

  __syncthreads();  // the only barrier

  const unsigned short* arow = &as_[(rg * 32 + col) * 264 + q * 8];
  const unsigned short* bbase = WeT2 + (size_t)cblk * 16384 + dg * 2048 + l * 8;
  #pragma unroll
  for (int kc = 0; kc < 4; ++kc) {
    #pragma unroll
    for (int st = 0; st < 4; ++st) {
      short8 a = *(const short8*)(arow + kc * 64 + st * 16);
      short8 b = *(const short8*)(bbase + (size_t)kc * 4096 + st * 512);
      acc = __builtin_amdgcn_mfma_f32_32x32x16_bf16(a, b, acc, 0, 0, 0);
    }
  }
  #pragma unroll
  for (int e = 0; e < 16; ++e) {
    const int row = (e & 3) + 8 * (e >> 2) + 4 * q;
    pe[(size_t)(m0 + rg * 32 + row) * ENC_COLS + c0 + dg * 32 + col] = acc[e];
  }
}

// ---------------------------------------------------------------------------
// Encoder post: sample + h (bf16, decoder-A-fragment global order) + Σ(Lq-Le).
// TWO waves per batch row (4 replicas each), 4096 waves = 4/SIMD.
// Block partial written to a private padded slot (NO atomics).
// grid 1024 x 256. h layout: [nblk 256][rg 2][st 4][q 2][col 32][j 8]
// ---------------------------------------------------------------------------
__global__ __launch_bounds__(256) void k_enc_post(
    const float* __restrict__ pe, const float* __restrict__ ue,
    const float* __restrict__ rr, unsigned short* __restrict__ h,
    float* __restrict__ part)
{
  const int lane = threadIdx.x & 63;
  const int w = threadIdx.x >> 6;
  const int gid = blockIdx.x * 4 + w;   // 0..4095
  const int b = gid >> 1;               // batch row
  const int j0 = (gid & 1) * 4;         // this wave's replica group
  const float* row = pe + (size_t)b * ENC_COLS + lane;

  float m[8], p[8], a[8];
  #pragma unroll
  for (int k = 0; k < K_C; ++k) {
    m[k] = row[k * 64]; p[k] = row[512 + k * 64]; a[k] = row[1024 + k * 64];
  }
  float amax = a[0];
  #pragma unroll
  for (int k = 1; k < K_C; ++k) amax = fmaxf(amax, a[k]);
  float sa = 0.f;
  #pragma unroll
  for (int k = 0; k < K_C; ++k) sa += __expf(a[k] - amax);
  const float lse_a = amax + __logf(sa);

  float cum[8];
  {
    float cs = 0.f;
    #pragma unroll
    for (int k = 0; k < K_C; ++k) { cs += __expf(a[k] - lse_a); cum[k] = cs; }
  }
  float ep[8];
  #pragma unroll
  for (int k = 0; k < K_C; ++k) ep[k] = __expf(p[k]);

  // this lane's fragment slot within a row's 64 k-values
  const int st = lane >> 4, qq = (lane >> 3) & 1, jj = lane & 7;

  float tot = 0.f;
  for (int jr = 0; jr < 4; ++jr) {
    const int j = j0 + jr;
    const int n = b + BATCH * j;
    const float rv = rr[(size_t)n * L_L + lane];
    const float uv = ue[(size_t)n * L_L + lane];
    int idx = 0;
    #pragma unroll
    for (int k = 0; k < K_C; ++k) idx += (rv > cum[k]) ? 1 : 0;
    idx = min(idx, K_C - 1);
    float msel = m[0], psel = p[0];
    #pragma unroll
    for (int k = 1; k < K_C; ++k) {
      const bool sel = (idx == k);
      msel = sel ? m[k] : msel;
      psel = sel ? p[k] : psel;
    }
    const float hv = fmaf(__expf(-0.5f * psel), uv, msel);

    const int nblk = n >> 6, rgn = (n >> 5) & 1, coln = n & 31;
    h[((((size_t)(nblk * 2 + rgn) * 4 + st) * 2 + qq) * 32 + coln) * 8 + jj] = f2bf(hv);

    float stt = 0.f;
    #pragma unroll
    for (int k = 0; k < K_C; ++k) {
      const float dd = hv - m[k];
      const float tt = a[k] + 0.5f * p[k] - 0.5f * ep[k] * dd * dd;
      stt += __expf(tt);
    }
    tot += -0.5f * hv * hv - (__logf(stt + 1e-30f) - lse_a);
  }
  #pragma unroll
  for (int off = 1; off < 64; off <<= 1) tot += __shfl_xor(tot, off, 64);
  __shared__ float red2[4];
  if (lane == 0) red2[w] = tot;
  __syncthreads();
  if (threadIdx.x == 0)
    part[(size_t)blockIdx.x * PART_STRIDE] = red2[0] + red2[1] + red2[2] + red2[3];
}

// ---------------------------------------------------------------------------
// Decoder: barrier-free fused MFMA GEMM + mixture epilogue.
// R16: SAME-COLUMN WAVE PACKING. Block = 128 rows x 32 cols, 4 waves = 4
// row-tiles of 32 (wave w owns rows (blockIdx.y*4+w)*32..+31), all waves
// share ONE (dg,dt) column group -> every B-fragment and bias address is
// IDENTICAL across the 4 co-resident waves: 4-way L1 dedup (R9 had 2-way),
// L2 B-traffic ~196->~98 MB, L1-hit latency on 3 of 4 loads. Per-wave
// registers byte-identical to R9 (~88+acc, no spill - R15's BM=128 spilled
// 15 MB scratch and regressed). Barrier-free; prefetch kept (R10 neutral).
// grid (8, 128): one cg per XCD -> per-XCD WdT2 slice ~98 KB, L2-resident.
// ---------------------------------------------------------------------------
__global__ __launch_bounds__(256, 2) void k_dec(
    const unsigned short* __restrict__ hF, const float* __restrict__ x,
    const unsigned short* __restrict__ WdT2, const float* __restrict__ bd,
    float* __restrict__ part)
{
  const int t = threadIdx.x;
  const int w = t >> 6, l = t & 63;
  const int col = l & 31, q = l >> 5;
  const int cg = blockIdx.x;              // 0..7
  const int dt = cg >> 1, dg = cg & 1;
  const int rt = blockIdx.y * 4 + w;      // 0..511, this wave's 32-row tile
  const int nblk = rt >> 1, rg = rt & 1;
  const int n0 = rt * 32;
  const int colD = dt * 64 + dg * 32 + col;

  // A fragments: 4 coalesced 16B loads (per-wave rows)
  const unsigned short* hbase = hF + ((size_t)(nblk * 2 + rg) * 4) * 512 + l * 8;
  short8 af[4];
  #pragma unroll
  for (int st = 0; st < 4; ++st) af[st] = *(const short8*)(hbase + st * 512);

  // x values for this lane's 16 C-elements (reused across all comps)
  float xv[16];
  #pragma unroll
  for (int e = 0; e < 16; ++e) {
    const int rw = (e & 3) + 8 * (e >> 2) + 4 * q;
    const int n = n0 + rw;
    xv[e] = x[(size_t)(n & (BATCH - 1)) * D_L + colD];
  }

  float s_a[16], s_t[16];
  #pragma unroll
  for (int e = 0; e < 16; ++e) { s_a[e] = 0.f; s_t[e] = 0.f; }

  // B base: identical for all 4 waves in the block (same dg, dt)
  const unsigned short* wbase = WdT2 + dg * 2048 + l * 8;
  const float* bdc = bd + colD;

  // prologue: comp 0's fragments + biases
  short8 bf[3][4];
  #pragma unroll
  for (int p = 0; p < 3; ++p) {
    const unsigned short* pb = wbase + ((size_t)p * 4 + dt) * 4096;
    #pragma unroll
    for (int st = 0; st < 4; ++st) bf[p][st] = *(const short8*)(pb + st * 512);
  }
  float bm  = bdc[0];
  float bpL = bdc[2048] * L2E;
  float baL = bdc[4096] * L2E;

  #pragma unroll 1
  for (int comp = 0; comp < K_C; ++comp) {
    float16_ am = {}, ap = {}, aa = {};
    #pragma unroll
    for (int st = 0; st < 4; ++st) {
      am = __builtin_amdgcn_mfma_f32_32x32x16_bf16(af[st], bf[0][st], am, 0, 0, 0);
      ap = __builtin_amdgcn_mfma_f32_32x32x16_bf16(af[st], bf[1][st], ap, 0, 0, 0);
      aa = __builtin_amdgcn_mfma_f32_32x32x16_bf16(af[st], bf[2][st], aa, 0, 0, 0);
    }

    const float cbm = bm, cbpL = bpL, cbaL = baL;

    // issue-early: next comp's loads fly while the epilogue below runs
    if (comp + 1 < K_C) {
      #pragma unroll
      for (int p = 0; p < 3; ++p) {
        const unsigned short* pb =
            wbase + ((size_t)((comp + 1) * 3 + p) * 4 + dt) * 4096;
        #pragma unroll
        for (int st = 0; st < 4; ++st) bf[p][st] = *(const short8*)(pb + st * 512);
      }
      bm  = bdc[(comp + 1) * 256];
      bpL = bdc[2048 + (comp + 1) * 256] * L2E;
      baL = bdc[4096 + (comp + 1) * 256] * L2E;
    }

    #pragma unroll
    for (int e = 0; e < 16; ++e) {
      const float dd  = xv[e] - (am[e] + cbm);
      const float lpL = ap[e] + cbpL;
      const float laL = aa[e] + cbaL;
      const float ex2 = EXP2F(lpL);                        // = e^{logp}
      const float t1  = fmaf(0.5f, lpL, laL);
      const float ttL = fmaf(-C_HL2E * ex2, dd * dd, t1);
      s_a[e] += EXP2F(laL);
      s_t[e] += EXP2F(ttL);
    }
  }

  float v = 0.f;
  #pragma unroll
  for (int e = 0; e < 16; ++e)
    v += LOG2F(s_t[e] + 1e-30f) - LOG2F(s_a[e]);
  v *= LN2;
  #pragma unroll
  for (int off = 1; off < 64; off <<= 1) v += __shfl_xor(v, off, 64);
  __shared__ float red[4];
  if (l == 0) red[w] = v;
  __syncthreads();
  if (t == 0) {
    const int bid = blockIdx.y * 8 + cg;   // 0..1023
    part[(size_t)(N_PART_ENC + bid) * PART_STRIDE] = red[0] + red[1] + red[2] + red[3];
  }
}

// ---------------------------------------------------------------------------
// final: reduce 2048 padded partials (coalesced 128B-stride reads) -> out.
// ---------------------------------------------------------------------------
__global__ __launch_bounds__(256) void k_final(
    const float* __restrict__ part, float* __restrict__ out)
{
  const int t = threadIdx.x;
  float s = 0.f;
  #pragma unroll
  for (int i = 0; i < N_PART_TOT / 256; ++i)
    s += part[(size_t)(t + i * 256) * PART_STRIDE];
  #pragma unroll
  for (int off = 1; off < 64; off <<= 1) s += __shfl_xor(s, off, 64);
  __shared__ float red[4];
  if ((t & 63) == 0) red[t >> 6] = s;
  __syncthreads();
  if (t == 0)
    out[0] = -((red[0] + red[1] + red[2] + red[3]) / (float)NTOT) + 128.0f * LOG2PI;
}

// ---------------------------------------------------------------------------
extern "C" void kernel_launch(void* const* d_in, const int* in_sizes, int n_in,
                              void* d_out, int out_size, void* d_ws, size_t ws_size,
                              hipStream_t stream)
{
  const float* x  = (const float*)d_in[0];
  const float* We = (const float*)d_in[1];
  const float* be = (const float*)d_in[2];
  const float* Wd = (const float*)d_in[3];
  const float* bd = (const float*)d_in[4];
  const float* ue = (const float*)d_in[5];
  const float* rr = (const float*)d_in[6];
  float* out = (float*)d_out;

  float* ws = (float*)d_ws;
  float* pe            = ws + OFF_PE;
  unsigned short* h    = (unsigned short*)(ws + OFF_H);
  unsigned short* WeT2 = (unsigned short*)(ws + OFF_WET2);
  unsigned short* WdT2 = (unsigned short*)(ws + OFF_WDT2);
  // partials overlay WeT2 (dead after k_enc); every slot rewritten per replay
  float* part          = ws + OFF_WET2;

  k_prep<<<dim3(192), 256, 0, stream>>>(We, Wd, WeT2, WdT2);
  k_enc<<<dim3(ENC_COLS / 64, BATCH / 64), 256, 0, stream>>>(x, WeT2, be, pe);
  k_enc_post<<<dim3(BATCH / 2), 256, 0, stream>>>(pe, ue, rr, h, part);
  k_dec<<<dim3(8, NTOT / 128), 256, 0, stream>>>(h, x, WdT2, bd, part);
  k_final<<<dim3(1), 256, 0, stream>>>(part, out);
}